// Round 8
// baseline (322.221 us; speedup 1.0000x reference)
//
#include <hip/hip_runtime.h>

// Problem constants
#define N_NODES 50000
#define N_EDGES 800000
#define NFEAT 512
#define NHID 256
#define NCLASS 64
#define NCOMB 576
#define NPAD 640             // NCOMB padded to 5x128 col-tiles (zero cols)
#define NSKIP 320            // NHID + NCLASS (skip0 | skip1), bf16, biases folded
#define RRELU_SLOPE 0.2291666666666667f

typedef __attribute__((ext_vector_type(8))) short bf16x8;
typedef __attribute__((ext_vector_type(4))) float f32x4;
typedef __attribute__((ext_vector_type(2))) float f32x2;

// async global->LDS, 16B per lane; dest = wave-uniform base + lane*16
#define GLOAD_LDS16(g, l)                                                      \
    __builtin_amdgcn_global_load_lds(                                          \
        (const __attribute__((address_space(1))) void*)(g),                    \
        (__attribute__((address_space(3))) void*)(l), 16, 0, 0)

__device__ __forceinline__ unsigned short f2bf(float f) {
    unsigned int x = __float_as_uint(f);
    unsigned int r = (x + 0x7fffu + ((x >> 16) & 1u)) >> 16;
    return (unsigned short)r;
}
__device__ __forceinline__ float bf2f(unsigned short u) {
    return __uint_as_float(((unsigned int)u) << 16);
}
__device__ __forceinline__ float bf_lo(unsigned int u) { return __uint_as_float(u << 16); }
__device__ __forceinline__ float bf_hi(unsigned int u) { return __uint_as_float(u & 0xffff0000u); }
// fp32 -> OCP e4m3 byte (RNE, saturating)
__device__ __forceinline__ unsigned char f2fp8(float v) {
    return (unsigned char)__builtin_amdgcn_cvt_pk_fp8_f32(v, v, 0, false);
}

// ---------------- mega-prep: all setup work + weight->out copies, one launch ----
#define S0 6400000            // cast x: float4 items (50000*512/4)
#define S1 7200000            // + edges (800000)
#define S2 7527680            // + Bt pack (640*512)
#define S3 7577681            // + rowptr (50001)
#define S4 7594065            // + w3t (16384)
#define S5 7594705            // + bias (640)
#define S6 7672529            // + weight copy, float4 items (77824)
#define PREP_BLOCKS ((S6 + 255) / 256)

__global__ __launch_bounds__(256)
void prep(const float* __restrict__ x, const int* __restrict__ erow,
          const int* __restrict__ ecol, const float* __restrict__ ev,
          const float* __restrict__ w1, const float* __restrict__ b1,
          const float* __restrict__ w2, const float* __restrict__ b2,
          const float* __restrict__ w3, const float* __restrict__ b3,
          const float* __restrict__ w4, const float* __restrict__ b4,
          unsigned short* __restrict__ xb, unsigned short* __restrict__ Bt,
          float* __restrict__ biasb, unsigned short* __restrict__ w3t,
          uint2* __restrict__ ep, int* __restrict__ rp,
          float* __restrict__ out) {
    int i = blockIdx.x * 256 + threadIdx.x;
    if (i >= S6) return;
    if (i < S0) {
        float4 v = ((const float4*)x)[i];
        ushort4 o;
        o.x = f2bf(v.x); o.y = f2bf(v.y); o.z = f2bf(v.z); o.w = f2bf(v.w);
        ((ushort4*)xb)[i] = o;
    } else if (i < S1) {
        int j = i - S0;
        uint2 e;
        e.x = (unsigned)ecol[j];
        e.y = __float_as_uint(ev[j]);
        ep[j] = e;
    } else if (i < S2) {
        int j = i - S1;
        int c = j >> 9;            // 0..639
        int k = j & 511;
        float v = 0.f;
        if (c < NHID)            v = w1[k * NHID + c];
        else if (c < 2 * NHID)   v = w2[k * NHID + (c - NHID)];
        else if (c < NCOMB)      v = w4[k * NCLASS + (c - 2 * NHID)];
        Bt[j] = f2bf(v);
    } else if (i < S3) {
        int n = i - S2;            // 0..50000
        int lo = 0, hi = N_EDGES;
        while (lo < hi) {
            int mid = (lo + hi) >> 1;
            if (erow[mid] < n) lo = mid + 1; else hi = mid;
        }
        rp[n] = lo;
    } else if (i < S4) {
        int j = i - S3;
        int c = j >> 8;            // NHID=256
        int k = j & 255;
        w3t[j] = f2bf(w3[k * NCLASS + c]);
    } else if (i < S5) {
        int b = i - S4;            // 0..639
        float v = 0.f;
        if (b >= NHID && b < 2 * NHID)       v = b1[b - NHID] + b2[b - NHID];
        else if (b >= 2 * NHID && b < NCOMB) v = b3[b - 2 * NHID] + b4[b - 2 * NHID];
        biasb[b] = v;
    } else {
        int j = i - S5;            // 0..77823
        float4* o4 = (float4*)out;
        if (j < 32768)        o4[800000 + j] = ((const float4*)w1)[j];
        else if (j < 65536)   o4[832768 + (j - 32768)] = ((const float4*)w2)[j - 32768];
        else if (j < 69632)   o4[865536 + (j - 65536)] = ((const float4*)w3)[j - 65536];
        else                  o4[869632 + (j - 69632)] = ((const float4*)w4)[j - 69632];
    }
}

// ---------------- bf16 MFMA GEMM, double-buffered single-barrier K-loop --------
// Tile 128 x BN, BK=64, K compile-time (full unroll). global_load_lds(16B)
// staging, XOR-octet swizzle. Pipeline: stage(i+1) AFTER the barrier, compute
// buf i — the vmcnt(0) drain at each barrier covers loads issued one full
// compute-phase earlier (round-7 structure exposed full staging latency/iter).
// MODE 0 (BN=128): XCD-co-schedule swizzle; cols<256 -> xw1 fp8; <576 -> skipb.
// MODE 1 (BN=64): 2D grid; fp8 out.
#define GBM 128
#define GBK 64
#define NCB0 5               // NPAD / 128 col-blocks in mode 0
#define NRP0 392             // row-panels in mode 0, padded to multiple of 8

template <int BN, int MODE, int K>
__global__ __launch_bounds__(256, 2)
void gemm_bf16(const unsigned short* __restrict__ A,   // [M,K] bf16 row-major
               const unsigned short* __restrict__ Bt,  // [*,K] bf16 row-major (B^T)
               const float* __restrict__ bias,
               unsigned char* __restrict__ C8,         // fp8 dest (mode0: xw1, mode1: hw3)
               unsigned short* __restrict__ skipb,     // mode 0 only
               int M, int NC) {
    constexpr int CF = BN / 32;               // col-frags per wave (4 or 2)
    constexpr int NIT = K / GBK;
    __shared__ unsigned short As[2][GBM * GBK];  // 2 x 16 KB
    __shared__ unsigned short Bs[2][BN * GBK];   // 2 x 16/8 KB
    int row0, col0;
    if (MODE == 0) {
        int b = blockIdx.x;
        int g = b / (8 * NCB0);
        int w = b % (8 * NCB0);
        int r = g * 8 + (w & 7);
        int c = w >> 3;
        if (r * GBM >= M) return;           // padded tail
        row0 = r * GBM;
        col0 = c * BN;
    } else {
        col0 = blockIdx.x * BN;
        row0 = blockIdx.y * GBM;
    }
    const int tid  = threadIdx.x;
    const int lane = tid & 63;
    const int wave = tid >> 6;
    const int wr = (wave >> 1) * 64;
    const int wc = (wave & 1) * (BN / 2);
    const int lm = lane & 15;
    const int l4 = lane >> 4;       // 0..3 (k-octet within 32-k chunk)
    const int sw = lm & 7;          // row-based swizzle key for frag reads

    // staging lane decomposition: 1024 B per wave-issue = 8 rows x 8 octets
    const int sub  = lane >> 3;     // row within 8-row chunk
    const int slot = lane & 7;      // LDS octet slot this lane fills
    const int goct = slot ^ sub;    // global octet to fetch for that slot

    auto stage = [&](int k0, unsigned short* Asb, unsigned short* Bsb) {
        #pragma unroll
        for (int p = 0; p < 4; ++p) {
            int chunk = wave * 4 + p;
            int gr = row0 + chunk * 8 + sub;
            if (gr > M - 1) gr = M - 1;     // clamp (dup rows only feed unsaved acc)
            GLOAD_LDS16(A + (size_t)gr * K + k0 + goct * 8, Asb + chunk * 512);
        }
        #pragma unroll
        for (int p = 0; p < BN / 32; ++p) {
            int chunk = wave * (BN / 32) + p;
            int rb = col0 + chunk * 8 + sub;
            GLOAD_LDS16(Bt + (size_t)rb * K + k0 + goct * 8, Bsb + chunk * 512);
        }
    };

    f32x4 acc[4][CF] = {};

    stage(0, As[0], Bs[0]);

    #pragma unroll
    for (int it = 0; it < NIT; ++it) {
        __syncthreads();    // drains buf[it] loads (issued one compute-phase ago)
        if (it + 1 < NIT) stage((it + 1) * GBK, As[(it + 1) & 1], Bs[(it + 1) & 1]);
        const unsigned short* Ac = As[it & 1];
        const unsigned short* Bc = Bs[it & 1];
        #pragma unroll
        for (int kk8 = 0; kk8 < GBK / 8; kk8 += 4) {   // two 32-k steps
            const int so = ((kk8 + l4) ^ sw) * 8;
            bf16x8 bfr[CF];
            #pragma unroll
            for (int j = 0; j < CF; ++j)
                bfr[j] = *(const bf16x8*)(Bc + (wc + j * 16 + lm) * 64 + so);
            #pragma unroll
            for (int i = 0; i < 4; ++i) {
                bf16x8 af = *(const bf16x8*)(Ac + (wr + i * 16 + lm) * 64 + so);
                #pragma unroll
                for (int j = 0; j < CF; ++j)
                    acc[i][j] = __builtin_amdgcn_mfma_f32_16x16x32_bf16(af, bfr[j], acc[i][j], 0, 0, 0);
            }
        }
    }

    // epilogue: C/D layout col=lane&15, row=(lane>>4)*4+reg
    #pragma unroll
    for (int i = 0; i < 4; ++i) {
        #pragma unroll
        for (int j = 0; j < CF; ++j) {
            int col = col0 + wc + j * 16 + lm;
            float bvv = (MODE == 0) ? bias[col] : 0.f;   // bias alloc'd NPAD, safe
            #pragma unroll
            for (int r = 0; r < 4; ++r) {
                int row = row0 + wr + i * 16 + l4 * 4 + r;
                if (row < M) {
                    float v = acc[i][j][r];
                    if (MODE == 0) {
                        if (col < NHID)       C8[(size_t)row * NHID + col] = f2fp8(v);
                        else if (col < NCOMB) skipb[(size_t)row * NSKIP + (col - NHID)] = f2bf(v + bvv);
                    } else {
                        C8[(size_t)row * NC + col] = f2fp8(v);
                    }
                }
            }
        }
    }
}

// ---------------- SpMM1 + skip0(+b1+b2) + RReLU -> hb (bf16) ----------------
// one wave per node; lane covers 4 features (fp8 dword gather); 8-edge unroll
__global__ __launch_bounds__(256)
void spmm1_rrelu(const int* __restrict__ rp, const uint2* __restrict__ ep,
                 const unsigned char* __restrict__ xw1q,
                 const unsigned short* __restrict__ skipb,
                 unsigned short* __restrict__ hb, int n_nodes) {
    int n = blockIdx.x * 4 + (threadIdx.x >> 6);
    if (n >= n_nodes) return;
    int lane = threadIdx.x & 63;
    int f = lane * 4;
    int lo = rp[n], hi = rp[n + 1];
    float s0 = 0.f, s1 = 0.f, s2 = 0.f, s3 = 0.f;
    int e = lo;
    for (; e + 7 < hi; e += 8) {
        uint2 ed[8];
        unsigned p[8];
        #pragma unroll
        for (int q = 0; q < 8; ++q) ed[q] = ep[e + q];
        #pragma unroll
        for (int q = 0; q < 8; ++q)
            p[q] = *(const unsigned*)(xw1q + (size_t)ed[q].x * NHID + f);
        #pragma unroll
        for (int q = 0; q < 8; ++q) {
            float v = __uint_as_float(ed[q].y);
            f32x2 ab = __builtin_amdgcn_cvt_pk_f32_fp8((int)p[q], false);
            f32x2 cd = __builtin_amdgcn_cvt_pk_f32_fp8((int)p[q], true);
            s0 += v * ab.x;
            s1 += v * ab.y;
            s2 += v * cd.x;
            s3 += v * cd.y;
        }
    }
    for (; e < hi; ++e) {
        uint2 ee = ep[e];
        float v = __uint_as_float(ee.y);
        unsigned p = *(const unsigned*)(xw1q + (size_t)ee.x * NHID + f);
        f32x2 ab = __builtin_amdgcn_cvt_pk_f32_fp8((int)p, false);
        f32x2 cd = __builtin_amdgcn_cvt_pk_f32_fp8((int)p, true);
        s0 += v * ab.x;
        s1 += v * ab.y;
        s2 += v * cd.x;
        s3 += v * cd.y;
    }
    ushort4 sk = *(const ushort4*)(skipb + (size_t)n * NSKIP + f);
    float v0 = s0 + bf2f(sk.x), v1 = s1 + bf2f(sk.y);
    float v2 = s2 + bf2f(sk.z), v3 = s3 + bf2f(sk.w);
    v0 = (v0 >= 0.f) ? v0 : v0 * RRELU_SLOPE;
    v1 = (v1 >= 0.f) ? v1 : v1 * RRELU_SLOPE;
    v2 = (v2 >= 0.f) ? v2 : v2 * RRELU_SLOPE;
    v3 = (v3 >= 0.f) ? v3 : v3 * RRELU_SLOPE;
    ushort4 o;
    o.x = f2bf(v0); o.y = f2bf(v1); o.z = f2bf(v2); o.w = f2bf(v3);
    *(ushort4*)(hb + (size_t)n * NHID + f) = o;
}

// ---------------- SpMM2 + skip1(+b3+b4) -> out ----------------
// one wave per node; QUARTER-wave (16 lanes) per edge, lane covers 4 fp8 feats;
// 4 edges concurrent per wave, 2-deep unroll = 8 in flight; shfl_xor(16,32) merge
__global__ __launch_bounds__(256)
void spmm2_out(const int* __restrict__ rp, const uint2* __restrict__ ep,
               const unsigned char* __restrict__ hw3q,
               const unsigned short* __restrict__ skipb,
               float* __restrict__ out, int n_nodes) {
    int n = blockIdx.x * 4 + (threadIdx.x >> 6);
    if (n >= n_nodes) return;
    int lane = threadIdx.x & 63;
    int q = lane >> 4;         // quarter 0..3 = edge slot
    int l = lane & 15;
    int f = l * 4;             // feature base
    int lo = rp[n], hi = rp[n + 1];
    float s0 = 0.f, s1 = 0.f, s2 = 0.f, s3 = 0.f;
    int e = lo + q;
    for (; e + 4 < hi; e += 8) {
        uint2 ea = ep[e], eb = ep[e + 4];
        unsigned pa = *(const unsigned*)(hw3q + (size_t)ea.x * NCLASS + f);
        unsigned pb = *(const unsigned*)(hw3q + (size_t)eb.x * NCLASS + f);
        float va = __uint_as_float(ea.y), vb = __uint_as_float(eb.y);
        f32x2 a0 = __builtin_amdgcn_cvt_pk_f32_fp8((int)pa, false);
        f32x2 a1 = __builtin_amdgcn_cvt_pk_f32_fp8((int)pa, true);
        f32x2 b0 = __builtin_amdgcn_cvt_pk_f32_fp8((int)pb, false);
        f32x2 b1 = __builtin_amdgcn_cvt_pk_f32_fp8((int)pb, true);
        s0 += va * a0.x + vb * b0.x;
        s1 += va * a0.y + vb * b0.y;
        s2 += va * a1.x + vb * b1.x;
        s3 += va * a1.y + vb * b1.y;
    }
    for (; e < hi; e += 4) {
        uint2 ee = ep[e];
        unsigned p = *(const unsigned*)(hw3q + (size_t)ee.x * NCLASS + f);
        float v = __uint_as_float(ee.y);
        f32x2 ab = __builtin_amdgcn_cvt_pk_f32_fp8((int)p, false);
        f32x2 cd = __builtin_amdgcn_cvt_pk_f32_fp8((int)p, true);
        s0 += v * ab.x;
        s1 += v * ab.y;
        s2 += v * cd.x;
        s3 += v * cd.y;
    }
    s0 += __shfl_xor(s0, 16); s0 += __shfl_xor(s0, 32);
    s1 += __shfl_xor(s1, 16); s1 += __shfl_xor(s1, 32);
    s2 += __shfl_xor(s2, 16); s2 += __shfl_xor(s2, 32);
    s3 += __shfl_xor(s3, 16); s3 += __shfl_xor(s3, 32);
    if (q == 0) {
        uint2 sv = *(const uint2*)(skipb + (size_t)n * NSKIP + NHID + f);
        float4 o;
        o.x = s0 + bf_lo(sv.x);
        o.y = s1 + bf_hi(sv.x);
        o.z = s2 + bf_lo(sv.y);
        o.w = s3 + bf_hi(sv.y);
        *(float4*)(out + (size_t)n * NCLASS + f) = o;
    }
}

extern "C" void kernel_launch(void* const* d_in, const int* in_sizes, int n_in,
                              void* d_out, int out_size, void* d_ws, size_t ws_size,
                              hipStream_t stream) {
    const float* x    = (const float*)d_in[0];
    const int*   erow = (const int*)d_in[1];
    const int*   ecol = (const int*)d_in[2];
    const float* ev   = (const float*)d_in[3];
    const float* w1   = (const float*)d_in[4];
    const float* b1   = (const float*)d_in[5];
    const float* w2   = (const float*)d_in[6];
    const float* b2   = (const float*)d_in[7];
    const float* w3   = (const float*)d_in[8];
    const float* b3   = (const float*)d_in[9];
    const float* w4   = (const float*)d_in[10];
    const float* b4   = (const float*)d_in[11];
    float* out = (float*)d_out;

    char* ws = (char*)d_ws;
    size_t off = 0;
    auto alloc = [&](size_t bytes) -> void* {
        off = (off + 255) & ~(size_t)255;
        void* p = ws + off;
        off += bytes;
        return p;
    };

    unsigned short* xb    = (unsigned short*)alloc((size_t)N_NODES * NFEAT * 2);
    unsigned short* Bt    = (unsigned short*)alloc((size_t)NFEAT * NPAD * 2);
    float*          biasb = (float*)alloc(NPAD * 4);
    unsigned char*  xw1q  = (unsigned char*)alloc((size_t)N_NODES * NHID);
    unsigned short* skipb = (unsigned short*)alloc((size_t)N_NODES * NSKIP * 2);
    unsigned short* hb    = (unsigned short*)alloc((size_t)N_NODES * NHID * 2);
    unsigned short* w3t   = (unsigned short*)alloc((size_t)NHID * NCLASS * 2);
    unsigned char*  hw3q  = (unsigned char*)alloc((size_t)N_NODES * NCLASS);
    int*            rp    = (int*)alloc((size_t)(N_NODES + 1) * 4);
    uint2*          ep    = (uint2*)alloc((size_t)N_EDGES * 8);

    // 1) all prep in one launch
    prep<<<PREP_BLOCKS, 256, 0, stream>>>(x, erow, ecol, ev, w1, b1, w2, b2, w3, b3,
                                          w4, b4, xb, Bt, biasb, w3t, ep, rp, out);

    // 2) fused GEMM: xb @ [w1|w2|w4|pad] -> xw1q (fp8) | skipb (bf16, +bias)
    gemm_bf16<128, 0, NFEAT><<<NRP0 * NCB0, 256, 0, stream>>>(xb, Bt, biasb, xw1q, skipb,
                                                              N_NODES, NPAD);

    // 3) spmm(xw1) + skip0 -> rrelu -> hb (bf16)
    spmm1_rrelu<<<(N_NODES + 3) / 4, 256, 0, stream>>>(rp, ep, xw1q, skipb, hb, N_NODES);

    // 4) hw3q = hb @ w3 (fp8 out)
    dim3 g2(NCLASS / 64, (N_NODES + GBM - 1) / GBM);
    gemm_bf16<64, 1, NHID><<<g2, 256, 0, stream>>>(hb, w3t, nullptr, hw3q, nullptr,
                                                   N_NODES, NCLASS);

    // 5) out = spmm(hw3) + skip1
    spmm2_out<<<(N_NODES + 3) / 4, 256, 0, stream>>>(rp, ep, hw3q, skipb, out, N_NODES);
}

// Round 9
// 312.994 us; speedup vs baseline: 1.0295x; 1.0295x over previous
//
#include <hip/hip_runtime.h>

// Problem constants
#define N_NODES 50000
#define N_EDGES 800000
#define NFEAT 512
#define NHID 256
#define NCLASS 64
#define NCOMB 576
#define NPAD 640             // NCOMB padded to 5x128 col-tiles (zero cols)
#define NSKIP 320            // NHID + NCLASS (skip0 | skip1), bf16, biases folded
#define RRELU_SLOPE 0.2291666666666667f

typedef __attribute__((ext_vector_type(8))) short bf16x8;
typedef __attribute__((ext_vector_type(4))) float f32x4;
typedef __attribute__((ext_vector_type(2))) float f32x2;

// async global->LDS, 16B per lane; dest = wave-uniform base + lane*16
#define GLOAD_LDS16(g, l)                                                      \
    __builtin_amdgcn_global_load_lds(                                          \
        (const __attribute__((address_space(1))) void*)(g),                    \
        (__attribute__((address_space(3))) void*)(l), 16, 0, 0)

__device__ __forceinline__ unsigned short f2bf(float f) {
    unsigned int x = __float_as_uint(f);
    unsigned int r = (x + 0x7fffu + ((x >> 16) & 1u)) >> 16;
    return (unsigned short)r;
}
__device__ __forceinline__ float bf2f(unsigned short u) {
    return __uint_as_float(((unsigned int)u) << 16);
}
__device__ __forceinline__ float bf_lo(unsigned int u) { return __uint_as_float(u << 16); }
__device__ __forceinline__ float bf_hi(unsigned int u) { return __uint_as_float(u & 0xffff0000u); }
// fp32 -> OCP e4m3 byte (RNE, saturating)
__device__ __forceinline__ unsigned char f2fp8(float v) {
    return (unsigned char)__builtin_amdgcn_cvt_pk_fp8_f32(v, v, 0, false);
}

// ---------------- mega-prep: all setup work + weight->out copies, one launch ----
#define S0 6400000            // cast x: float4 items (50000*512/4)
#define S1 7200000            // + edges (800000)
#define S2 7527680            // + Bt pack (640*512)
#define S3 7577681            // + rowptr (50001)
#define S4 7594065            // + w3t (16384)
#define S5 7594705            // + bias (640)
#define S6 7672529            // + weight copy, float4 items (77824)
#define PREP_BLOCKS ((S6 + 255) / 256)

__global__ __launch_bounds__(256)
void prep(const float* __restrict__ x, const int* __restrict__ erow,
          const int* __restrict__ ecol, const float* __restrict__ ev,
          const float* __restrict__ w1, const float* __restrict__ b1,
          const float* __restrict__ w2, const float* __restrict__ b2,
          const float* __restrict__ w3, const float* __restrict__ b3,
          const float* __restrict__ w4, const float* __restrict__ b4,
          unsigned short* __restrict__ xb, unsigned short* __restrict__ Bt,
          float* __restrict__ biasb, unsigned short* __restrict__ w3t,
          uint2* __restrict__ ep, int* __restrict__ rp,
          float* __restrict__ out) {
    int i = blockIdx.x * 256 + threadIdx.x;
    if (i >= S6) return;
    if (i < S0) {
        float4 v = ((const float4*)x)[i];
        ushort4 o;
        o.x = f2bf(v.x); o.y = f2bf(v.y); o.z = f2bf(v.z); o.w = f2bf(v.w);
        ((ushort4*)xb)[i] = o;
    } else if (i < S1) {
        int j = i - S0;
        uint2 e;
        e.x = (unsigned)ecol[j];
        e.y = __float_as_uint(ev[j]);
        ep[j] = e;
    } else if (i < S2) {
        int j = i - S1;
        int c = j >> 9;            // 0..639
        int k = j & 511;
        float v = 0.f;
        if (c < NHID)            v = w1[k * NHID + c];
        else if (c < 2 * NHID)   v = w2[k * NHID + (c - NHID)];
        else if (c < NCOMB)      v = w4[k * NCLASS + (c - 2 * NHID)];
        Bt[j] = f2bf(v);
    } else if (i < S3) {
        int n = i - S2;            // 0..50000
        int lo = 0, hi = N_EDGES;
        while (lo < hi) {
            int mid = (lo + hi) >> 1;
            if (erow[mid] < n) lo = mid + 1; else hi = mid;
        }
        rp[n] = lo;
    } else if (i < S4) {
        int j = i - S3;
        int c = j >> 8;            // NHID=256
        int k = j & 255;
        w3t[j] = f2bf(w3[k * NCLASS + c]);
    } else if (i < S5) {
        int b = i - S4;            // 0..639
        float v = 0.f;
        if (b >= NHID && b < 2 * NHID)       v = b1[b - NHID] + b2[b - NHID];
        else if (b >= 2 * NHID && b < NCOMB) v = b3[b - 2 * NHID] + b4[b - 2 * NHID];
        biasb[b] = v;
    } else {
        int j = i - S5;            // 0..77823
        float4* o4 = (float4*)out;
        if (j < 32768)        o4[800000 + j] = ((const float4*)w1)[j];
        else if (j < 65536)   o4[832768 + (j - 32768)] = ((const float4*)w2)[j - 32768];
        else if (j < 69632)   o4[865536 + (j - 65536)] = ((const float4*)w3)[j - 65536];
        else                  o4[869632 + (j - 69632)] = ((const float4*)w4)[j - 69632];
    }
}

// ---------------- bf16 MFMA GEMM: BK=32, double-buffered, 1 barrier/iter -------
// LDS row = 32 bf16 = 64 B = 4 octets of 16 B. Swizzle: octet g of row r is
// stored at slot s = g ^ (r&3) ^ ((r>>2)&3)  (plain g^(r&3) would 4-way
// conflict: rows 0,4,8,12 all land slot g for lanes of one l4 group; the extra
// ^(r>>2) rotates them apart -> <=2-way, free).
// Pipeline: barrier; stage(it+1) into buf^1; compute buf — each barrier's
// vmcnt(0) drain covers loads issued one compute-phase (~700cy) earlier.
// dbuf total LDS = 2*(8+8) = 32 KB (mode0), same as R7 single-buffer -> keeps
// ~4 blocks/CU (R8's 64 KB dbuf dropped to 2 blocks/CU and regressed).
// MODE 0 (BN=128): XCD-co-schedule swizzle; cols<256 -> xw1 fp8; <576 -> skipb.
// MODE 1 (BN=64): 2D grid; fp8 out.
#define GBM 128
#define GBK 32
#define NCB0 5               // NPAD / 128 col-blocks in mode 0
#define NRP0 392             // row-panels in mode 0, padded to multiple of 8

template <int BN, int MODE, int K>
__global__ __launch_bounds__(256, 4)
void gemm_bf16(const unsigned short* __restrict__ A,   // [M,K] bf16 row-major
               const unsigned short* __restrict__ Bt,  // [*,K] bf16 row-major (B^T)
               const float* __restrict__ bias,
               unsigned char* __restrict__ C8,         // fp8 dest (mode0: xw1, mode1: hw3)
               unsigned short* __restrict__ skipb,     // mode 0 only
               int M, int NC) {
    constexpr int CF = BN / 32;               // col-frags per wave (4 or 2)
    constexpr int NIT = K / GBK;
    __shared__ unsigned short As[2][GBM * GBK];  // 2 x 8 KB
    __shared__ unsigned short Bs[2][BN * GBK];   // 2 x 8 KB / 2 x 4 KB
    int row0, col0;
    if (MODE == 0) {
        int b = blockIdx.x;
        int g = b / (8 * NCB0);
        int w = b % (8 * NCB0);
        int r = g * 8 + (w & 7);
        int c = w >> 3;
        if (r * GBM >= M) return;           // padded tail
        row0 = r * GBM;
        col0 = c * BN;
    } else {
        col0 = blockIdx.x * BN;
        row0 = blockIdx.y * GBM;
    }
    const int tid  = threadIdx.x;
    const int lane = tid & 63;
    const int wave = tid >> 6;
    const int wr = (wave >> 1) * 64;
    const int wc = (wave & 1) * (BN / 2);
    const int lm = lane & 15;
    const int l4 = lane >> 4;       // 0..3 = k-octet index
    // frag-read LDS byte->elem offset: slot = l4 ^ (lm&3) ^ ((lm>>2)&3), x8 elems
    const int so = ((l4 ^ (lm & 3) ^ ((lm >> 2) & 3))) * 8;

    // staging lane decomposition: 1024 B per wave-issue = 16 rows x 4 octets
    const int sub  = lane >> 2;     // row within 16-row chunk
    const int slot = lane & 3;      // LDS octet slot this lane fills
    const int goct = slot ^ (sub & 3) ^ ((sub >> 2) & 3);   // global octet for slot

    auto stage = [&](int k0, int buf) {
        unsigned short* Asb = As[buf];
        unsigned short* Bsb = Bs[buf];
        #pragma unroll
        for (int p = 0; p < 2; ++p) {                 // A: 8 chunks of 16 rows
            int chunk = wave * 2 + p;
            int gr = row0 + chunk * 16 + sub;
            if (gr > M - 1) gr = M - 1;               // clamp (dups feed unsaved acc)
            GLOAD_LDS16(A + (size_t)gr * K + k0 + goct * 8, Asb + chunk * 512);
        }
        #pragma unroll
        for (int p = 0; p < BN / 64; ++p) {           // B: BN/16 chunks
            int chunk = wave * (BN / 64) + p;
            int rb = col0 + chunk * 16 + sub;
            GLOAD_LDS16(Bt + (size_t)rb * K + k0 + goct * 8, Bsb + chunk * 512);
        }
    };

    f32x4 acc[4][CF] = {};

    stage(0, 0);

    #pragma unroll
    for (int it = 0; it < NIT; ++it) {
        __syncthreads();   // drains buf[it] loads (issued one compute-phase ago)
        if (it + 1 < NIT) stage((it + 1) * GBK, (it + 1) & 1);
        const unsigned short* Ac = As[it & 1];
        const unsigned short* Bc = Bs[it & 1];
        bf16x8 bfr[CF];
        #pragma unroll
        for (int j = 0; j < CF; ++j)
            bfr[j] = *(const bf16x8*)(Bc + (wc + j * 16 + lm) * 32 + so);
        #pragma unroll
        for (int i = 0; i < 4; ++i) {
            bf16x8 af = *(const bf16x8*)(Ac + (wr + i * 16 + lm) * 32 + so);
            #pragma unroll
            for (int j = 0; j < CF; ++j)
                acc[i][j] = __builtin_amdgcn_mfma_f32_16x16x32_bf16(af, bfr[j], acc[i][j], 0, 0, 0);
        }
    }

    // epilogue: C/D layout col=lane&15, row=(lane>>4)*4+reg
    #pragma unroll
    for (int i = 0; i < 4; ++i) {
        #pragma unroll
        for (int j = 0; j < CF; ++j) {
            int col = col0 + wc + j * 16 + lm;
            float bvv = (MODE == 0) ? bias[col] : 0.f;   // bias alloc'd NPAD, safe
            #pragma unroll
            for (int r = 0; r < 4; ++r) {
                int row = row0 + wr + i * 16 + l4 * 4 + r;
                if (row < M) {
                    float v = acc[i][j][r];
                    if (MODE == 0) {
                        if (col < NHID)       C8[(size_t)row * NHID + col] = f2fp8(v);
                        else if (col < NCOMB) skipb[(size_t)row * NSKIP + (col - NHID)] = f2bf(v + bvv);
                    } else {
                        C8[(size_t)row * NC + col] = f2fp8(v);
                    }
                }
            }
        }
    }
}

// ---------------- SpMM1 + skip0(+b1+b2) + RReLU -> hb (bf16) ----------------
// one wave per node; lane covers 4 features (fp8 dword gather); 8-edge unroll
__global__ __launch_bounds__(256)
void spmm1_rrelu(const int* __restrict__ rp, const uint2* __restrict__ ep,
                 const unsigned char* __restrict__ xw1q,
                 const unsigned short* __restrict__ skipb,
                 unsigned short* __restrict__ hb, int n_nodes) {
    int n = blockIdx.x * 4 + (threadIdx.x >> 6);
    if (n >= n_nodes) return;
    int lane = threadIdx.x & 63;
    int f = lane * 4;
    int lo = rp[n], hi = rp[n + 1];
    float s0 = 0.f, s1 = 0.f, s2 = 0.f, s3 = 0.f;
    int e = lo;
    for (; e + 7 < hi; e += 8) {
        uint2 ed[8];
        unsigned p[8];
        #pragma unroll
        for (int q = 0; q < 8; ++q) ed[q] = ep[e + q];
        #pragma unroll
        for (int q = 0; q < 8; ++q)
            p[q] = *(const unsigned*)(xw1q + (size_t)ed[q].x * NHID + f);
        #pragma unroll
        for (int q = 0; q < 8; ++q) {
            float v = __uint_as_float(ed[q].y);
            f32x2 ab = __builtin_amdgcn_cvt_pk_f32_fp8((int)p[q], false);
            f32x2 cd = __builtin_amdgcn_cvt_pk_f32_fp8((int)p[q], true);
            s0 += v * ab.x;
            s1 += v * ab.y;
            s2 += v * cd.x;
            s3 += v * cd.y;
        }
    }
    for (; e < hi; ++e) {
        uint2 ee = ep[e];
        float v = __uint_as_float(ee.y);
        unsigned p = *(const unsigned*)(xw1q + (size_t)ee.x * NHID + f);
        f32x2 ab = __builtin_amdgcn_cvt_pk_f32_fp8((int)p, false);
        f32x2 cd = __builtin_amdgcn_cvt_pk_f32_fp8((int)p, true);
        s0 += v * ab.x;
        s1 += v * ab.y;
        s2 += v * cd.x;
        s3 += v * cd.y;
    }
    ushort4 sk = *(const ushort4*)(skipb + (size_t)n * NSKIP + f);
    float v0 = s0 + bf2f(sk.x), v1 = s1 + bf2f(sk.y);
    float v2 = s2 + bf2f(sk.z), v3 = s3 + bf2f(sk.w);
    v0 = (v0 >= 0.f) ? v0 : v0 * RRELU_SLOPE;
    v1 = (v1 >= 0.f) ? v1 : v1 * RRELU_SLOPE;
    v2 = (v2 >= 0.f) ? v2 : v2 * RRELU_SLOPE;
    v3 = (v3 >= 0.f) ? v3 : v3 * RRELU_SLOPE;
    ushort4 o;
    o.x = f2bf(v0); o.y = f2bf(v1); o.z = f2bf(v2); o.w = f2bf(v3);
    *(ushort4*)(hb + (size_t)n * NHID + f) = o;
}

// ---------------- SpMM2 + skip1(+b3+b4) -> out ----------------
// one wave per node; QUARTER-wave (16 lanes) per edge, lane covers 4 fp8 feats;
// 4 edges concurrent per wave, 2-deep unroll = 8 in flight; shfl_xor(16,32) merge
__global__ __launch_bounds__(256)
void spmm2_out(const int* __restrict__ rp, const uint2* __restrict__ ep,
               const unsigned char* __restrict__ hw3q,
               const unsigned short* __restrict__ skipb,
               float* __restrict__ out, int n_nodes) {
    int n = blockIdx.x * 4 + (threadIdx.x >> 6);
    if (n >= n_nodes) return;
    int lane = threadIdx.x & 63;
    int q = lane >> 4;         // quarter 0..3 = edge slot
    int l = lane & 15;
    int f = l * 4;             // feature base
    int lo = rp[n], hi = rp[n + 1];
    float s0 = 0.f, s1 = 0.f, s2 = 0.f, s3 = 0.f;
    int e = lo + q;
    for (; e + 4 < hi; e += 8) {
        uint2 ea = ep[e], eb = ep[e + 4];
        unsigned pa = *(const unsigned*)(hw3q + (size_t)ea.x * NCLASS + f);
        unsigned pb = *(const unsigned*)(hw3q + (size_t)eb.x * NCLASS + f);
        float va = __uint_as_float(ea.y), vb = __uint_as_float(eb.y);
        f32x2 a0 = __builtin_amdgcn_cvt_pk_f32_fp8((int)pa, false);
        f32x2 a1 = __builtin_amdgcn_cvt_pk_f32_fp8((int)pa, true);
        f32x2 b0 = __builtin_amdgcn_cvt_pk_f32_fp8((int)pb, false);
        f32x2 b1 = __builtin_amdgcn_cvt_pk_f32_fp8((int)pb, true);
        s0 += va * a0.x + vb * b0.x;
        s1 += va * a0.y + vb * b0.y;
        s2 += va * a1.x + vb * b1.x;
        s3 += va * a1.y + vb * b1.y;
    }
    for (; e < hi; e += 4) {
        uint2 ee = ep[e];
        unsigned p = *(const unsigned*)(hw3q + (size_t)ee.x * NCLASS + f);
        float v = __uint_as_float(ee.y);
        f32x2 ab = __builtin_amdgcn_cvt_pk_f32_fp8((int)p, false);
        f32x2 cd = __builtin_amdgcn_cvt_pk_f32_fp8((int)p, true);
        s0 += v * ab.x;
        s1 += v * ab.y;
        s2 += v * cd.x;
        s3 += v * cd.y;
    }
    s0 += __shfl_xor(s0, 16); s0 += __shfl_xor(s0, 32);
    s1 += __shfl_xor(s1, 16); s1 += __shfl_xor(s1, 32);
    s2 += __shfl_xor(s2, 16); s2 += __shfl_xor(s2, 32);
    s3 += __shfl_xor(s3, 16); s3 += __shfl_xor(s3, 32);
    if (q == 0) {
        uint2 sv = *(const uint2*)(skipb + (size_t)n * NSKIP + NHID + f);
        float4 o;
        o.x = s0 + bf_lo(sv.x);
        o.y = s1 + bf_hi(sv.x);
        o.z = s2 + bf_lo(sv.y);
        o.w = s3 + bf_hi(sv.y);
        *(float4*)(out + (size_t)n * NCLASS + f) = o;
    }
}

extern "C" void kernel_launch(void* const* d_in, const int* in_sizes, int n_in,
                              void* d_out, int out_size, void* d_ws, size_t ws_size,
                              hipStream_t stream) {
    const float* x    = (const float*)d_in[0];
    const int*   erow = (const int*)d_in[1];
    const int*   ecol = (const int*)d_in[2];
    const float* ev   = (const float*)d_in[3];
    const float* w1   = (const float*)d_in[4];
    const float* b1   = (const float*)d_in[5];
    const float* w2   = (const float*)d_in[6];
    const float* b2   = (const float*)d_in[7];
    const float* w3   = (const float*)d_in[8];
    const float* b3   = (const float*)d_in[9];
    const float* w4   = (const float*)d_in[10];
    const float* b4   = (const float*)d_in[11];
    float* out = (float*)d_out;

    char* ws = (char*)d_ws;
    size_t off = 0;
    auto alloc = [&](size_t bytes) -> void* {
        off = (off + 255) & ~(size_t)255;
        void* p = ws + off;
        off += bytes;
        return p;
    };

    unsigned short* xb    = (unsigned short*)alloc((size_t)N_NODES * NFEAT * 2);
    unsigned short* Bt    = (unsigned short*)alloc((size_t)NFEAT * NPAD * 2);
    float*          biasb = (float*)alloc(NPAD * 4);
    unsigned char*  xw1q  = (unsigned char*)alloc((size_t)N_NODES * NHID);
    unsigned short* skipb = (unsigned short*)alloc((size_t)N_NODES * NSKIP * 2);
    unsigned short* hb    = (unsigned short*)alloc((size_t)N_NODES * NHID * 2);
    unsigned short* w3t   = (unsigned short*)alloc((size_t)NHID * NCLASS * 2);
    unsigned char*  hw3q  = (unsigned char*)alloc((size_t)N_NODES * NCLASS);
    int*            rp    = (int*)alloc((size_t)(N_NODES + 1) * 4);
    uint2*          ep    = (uint2*)alloc((size_t)N_EDGES * 8);

    // 1) all prep in one launch
    prep<<<PREP_BLOCKS, 256, 0, stream>>>(x, erow, ecol, ev, w1, b1, w2, b2, w3, b3,
                                          w4, b4, xb, Bt, biasb, w3t, ep, rp, out);

    // 2) fused GEMM: xb @ [w1|w2|w4|pad] -> xw1q (fp8) | skipb (bf16, +bias)
    gemm_bf16<128, 0, NFEAT><<<NRP0 * NCB0, 256, 0, stream>>>(xb, Bt, biasb, xw1q, skipb,
                                                              N_NODES, NPAD);

    // 3) spmm(xw1) + skip0 -> rrelu -> hb (bf16)
    spmm1_rrelu<<<(N_NODES + 3) / 4, 256, 0, stream>>>(rp, ep, xw1q, skipb, hb, N_NODES);

    // 4) hw3q = hb @ w3 (fp8 out)
    dim3 g2(NCLASS / 64, (N_NODES + GBM - 1) / GBM);
    gemm_bf16<64, 1, NHID><<<g2, 256, 0, stream>>>(hb, w3t, nullptr, hw3q, nullptr,
                                                   N_NODES, NCLASS);

    // 5) out = spmm(hw3) + skip1
    spmm2_out<<<(N_NODES + 3) / 4, 256, 0, stream>>>(rp, ep, hw3q, skipb, out, N_NODES);
}